// Round 3
// baseline (816.511 us; speedup 1.0000x reference)
//
#include <hip/hip_runtime.h>
#include <stdint.h>

// Two-kernel split, barrier-free streaming GEMM:
//  K1 conv_kernel: conv1(1->128)+relu+depthwise conv2+relu -> x bf16 [B][I][9456] in d_ws.
//     XCD-swizzled so instrument i's writers land on XCD i&7.
//  K2 gemm_kernel: out = sigmoid(x . wfc^T + bfc). 256 blocks (i x nh, pair-swizzled to
//     same XCD) x 768 thr = 12 waves = (3 n-tiles x 4 K-quarters). MFMA operands loaded
//     DIRECTLY from global (A: bf16 from x; B: fp32 nontemporal from wfc, cvt in reg),
//     depth-3 register pipeline, NO barriers in K-loop -> per-wave vmcnt(N) waits only.
//     One __syncthreads for the 4-way K-partial reduction via LDS at the end.
// Fallback: round-1 fused kernel if ws too small.

namespace {
constexpr int kB = 64, kI = 128, kN = 88, kT = 201, kF = 52;
constexpr int kT2 = 197, kF2 = 48;
constexpr int kFTOT = kT2 * kF2;  // 9456
constexpr int kNH = 44;
constexpr int kTHREADS = 384;   // conv / fallback
constexpr int kGTHREADS = 768;  // gemm
constexpr int kKQ = 2368;       // K per quarter (74 steps of 32; 4*2368=9472 >= 9456)
constexpr int kSTEPS = 74;
// fallback fused kernel
constexpr int kLDK = 200;
constexpr int kSLABS = 50;

typedef float f32x4 __attribute__((ext_vector_type(4)));
typedef __bf16 bf16x8 __attribute__((ext_vector_type(8)));
typedef unsigned short u16x8 __attribute__((ext_vector_type(8)));
typedef unsigned short u16x4 __attribute__((ext_vector_type(4)));

__device__ __forceinline__ unsigned short bf16_rne(float f) {
  unsigned int u = __float_as_uint(f);
  u += 0x7fffu + ((u >> 16) & 1u);
  return (unsigned short)(u >> 16);
}

__device__ __forceinline__ bf16x8 as_bf16x8(u16x8 v) {
  union { u16x8 u; bf16x8 b; } c; c.u = v; return c.b;
}

__device__ __forceinline__ void loadrow(float* d, const float* p) {
  float4 a = *(const float4*)p;
  float4 b = *(const float4*)(p + 4);
  float4 c = *(const float4*)(p + 8);
  d[0] = a.x; d[1] = a.y; d[2] = a.z;  d[3] = a.w;
  d[4] = b.x; d[5] = b.y; d[6] = b.z;  d[7] = b.w;
  d[8] = c.x; d[9] = c.y; d[10] = c.z; d[11] = c.w;
}

__device__ __forceinline__ void c1row(float* o, const float* r0, const float* r1,
                                      const float* r2, const float* w, float bias) {
#pragma unroll
  for (int c = 0; c < 10; ++c) {
    float v = bias;
    v += r0[c] * w[0]; v += r0[c + 1] * w[1]; v += r0[c + 2] * w[2];
    v += r1[c] * w[3]; v += r1[c + 1] * w[4]; v += r1[c + 2] * w[5];
    v += r2[c] * w[6]; v += r2[c + 1] * w[7]; v += r2[c + 2] * w[8];
    o[c] = fmaxf(v, 0.0f);
  }
}
}  // namespace

// ---------------------------------------------------------------- K1: conv
namespace {
__device__ __forceinline__ void conv_step(const float* dbase, int lrow,
    float* dNew, const float* dP2, const float* dP1,
    float* c1n, const float* c1x, const float* c1y,
    unsigned short* xout, int t2,
    const float* w1r, float b1r, const float* w2r, float b2r) {
  loadrow(dNew, dbase + lrow * kF);
  c1row(c1n, dP2, dP1, dNew, w1r, b1r);
  u16x8 o8;
#pragma unroll
  for (int c = 0; c < 8; ++c) {
    float v = b2r;
    v += c1x[c] * w2r[0] + c1x[c + 1] * w2r[1] + c1x[c + 2] * w2r[2];
    v += c1y[c] * w2r[3] + c1y[c + 1] * w2r[4] + c1y[c + 2] * w2r[5];
    v += c1n[c] * w2r[6] + c1n[c + 1] * w2r[7] + c1n[c + 2] * w2r[8];
    o8[c] = bf16_rne(fmaxf(v, 0.0f));
  }
  *(u16x8*)(xout + (size_t)t2 * kF2) = o8;
}
}  // namespace

__global__ __launch_bounds__(kTHREADS, 3) void conv_kernel(
    const float* __restrict__ data, const float* __restrict__ w1,
    const float* __restrict__ b1, const float* __restrict__ w2,
    const float* __restrict__ b2, unsigned short* __restrict__ x) {
  const int j = blockIdx.x;
  const int i = ((j >> 5) << 3) | (j & 7);  // XCD(i) = i&7, matches gemm readers
  const int rg = (j >> 3) & 3;
  const int base = rg * 50;
  const int ntrip = (rg == 3) ? 15 : 16;  // rows: 50/50/50/47
  const int tid = threadIdx.x;
  const int bb = tid / 6, oc = tid - bb * 6;
  const float* dbase = data + bb * (kT * kF) + oc * 8;
  unsigned short* xout = x + ((size_t)(bb * kI + i)) * kFTOT + oc * 8;

  float w1r[9], w2r[9];
#pragma unroll
  for (int jj = 0; jj < 9; ++jj) { w1r[jj] = w1[i * 9 + jj]; w2r[jj] = w2[i * 9 + jj]; }
  const float b1r = b1[i], b2r = b2[i];

  float dA[12], dB[12], dC[12], c1A[10], c1B[10], c1C[10];
  loadrow(dB, dbase + (base + 0) * kF);
  loadrow(dC, dbase + (base + 1) * kF);
  loadrow(dA, dbase + (base + 2) * kF);
  c1row(c1A, dB, dC, dA, w1r, b1r);
  loadrow(dB, dbase + (base + 3) * kF);
  c1row(c1B, dC, dA, dB, w1r, b1r);

  int t2 = base;
  for (int tt = 0; tt < ntrip; ++tt, t2 += 3) {
    conv_step(dbase, t2 + 4, dC, dA, dB, c1C, c1A, c1B, xout, t2, w1r, b1r, w2r, b2r);
    conv_step(dbase, t2 + 5, dA, dB, dC, c1A, c1B, c1C, xout, t2 + 1, w1r, b1r, w2r, b2r);
    conv_step(dbase, t2 + 6, dB, dC, dA, c1B, c1C, c1A, xout, t2 + 2, w1r, b1r, w2r, b2r);
  }
  conv_step(dbase, t2 + 4, dC, dA, dB, c1C, c1A, c1B, xout, t2, w1r, b1r, w2r, b2r);
  conv_step(dbase, t2 + 5, dA, dB, dC, c1A, c1B, c1C, xout, t2 + 1, w1r, b1r, w2r, b2r);
}

// ---------------------------------------------------------------- K2: gemm
__global__ __launch_bounds__(kGTHREADS, 1) void gemm_kernel(
    const unsigned short* __restrict__ x, const float* __restrict__ wfc,
    const float* __restrict__ bfc, float* __restrict__ out) {
  __shared__ f32x4 red[3][3][4][64];  // [nt][kq-1][mt][lane] = 36 KB

  const int j = blockIdx.x;
  const int i = ((j >> 4) << 3) | (j & 7);  // pairs (i,nh=0/1) share XCD j&7
  const int nh = (j >> 3) & 1;
  const int nbase = nh * kNH;
  const int tid = threadIdx.x;
  const int wv = tid >> 6, ln = tid & 63;
  const int nt = wv % 3, kq = wv / 3;
  const int lc = ln & 15, lq = ln >> 4;
  const int kqb = kq * kKQ;

  // A row pointers: m = mt*16 + lc (bf16, already MFMA A-operand friendly)
  const unsigned short* xr[4];
#pragma unroll
  for (int mt = 0; mt < 4; ++mt)
    xr[mt] = x + ((size_t)((mt * 16 + lc) * kI + i)) * kFTOT;
  // B row: n = nbase + nt*16 + lc (clamped: nt=2 lanes lc>=12 are pad, discarded)
  int brow = i * kN + nbase + nt * 16 + lc;
  if (brow > kI * kN - 1) brow = kI * kN - 1;
  const float* wr = wfc + (size_t)brow * kFTOT;

  f32x4 acc[4];
#pragma unroll
  for (int mt = 0; mt < 4; ++mt) acc[mt] = f32x4{0.f, 0.f, 0.f, 0.f};

  struct Set { u16x8 a[4]; f32x4 w0, w1; };
  Set S0, S1, S2;

  auto issue = [&](Set& S, int s) {
    const int k0 = kqb + s * 32 + lq * 8;
#pragma unroll
    for (int mt = 0; mt < 4; ++mt) S.a[mt] = *(const u16x8*)(xr[mt] + k0);
    const f32x4 z = {0.f, 0.f, 0.f, 0.f};
    S.w0 = (k0 + 4 <= kFTOT) ? __builtin_nontemporal_load((const f32x4*)(wr + k0)) : z;
    S.w1 = (k0 + 8 <= kFTOT) ? __builtin_nontemporal_load((const f32x4*)(wr + k0 + 4)) : z;
  };
  auto consume = [&](Set& S) {
    u16x8 bb;
#pragma unroll
    for (int e = 0; e < 4; ++e) {
      bb[e] = bf16_rne(S.w0[e]);
      bb[e + 4] = bf16_rne(S.w1[e]);
    }
    bf16x8 bf = as_bf16x8(bb);
#pragma unroll
    for (int mt = 0; mt < 4; ++mt)
      acc[mt] = __builtin_amdgcn_mfma_f32_16x16x32_bf16(as_bf16x8(S.a[mt]), bf,
                                                        acc[mt], 0, 0, 0);
  };

  issue(S0, 0); issue(S1, 1); issue(S2, 2);
  for (int s = 0; s < 72; s += 3) {
    consume(S0); if (s + 3 < kSTEPS) issue(S0, s + 3);
    consume(S1); if (s + 4 < kSTEPS) issue(S1, s + 4);
    consume(S2); if (s + 5 < kSTEPS) issue(S2, s + 5);
  }
  consume(S0);  // step 72
  consume(S1);  // step 73

  // ---- reduce K-quarters: kq>0 waves park partials in LDS, kq==0 sums ----
  if (kq != 0) {
#pragma unroll
    for (int mt = 0; mt < 4; ++mt) red[nt][kq - 1][mt][ln] = acc[mt];
  }
  __syncthreads();
  if (kq == 0) {
#pragma unroll
    for (int mt = 0; mt < 4; ++mt) {
#pragma unroll
      for (int q = 0; q < 3; ++q) {
        f32x4 p = red[nt][q][mt][ln];
        acc[mt][0] += p[0]; acc[mt][1] += p[1];
        acc[mt][2] += p[2]; acc[mt][3] += p[3];
      }
    }
    const int nl = nt * 16 + lc;
    if (nl < kNH) {
      const int ng = nbase + nl;
      const float bias = bfc[i * kN + ng];
#pragma unroll
      for (int mt = 0; mt < 4; ++mt) {
#pragma unroll
        for (int r = 0; r < 4; ++r) {
          const int b0 = mt * 16 + lq * 4 + r;
          const float v = acc[mt][r] + bias;
          out[(size_t)(b0 * kI + i) * kN + ng] = 1.0f / (1.0f + __expf(-v));
        }
      }
    }
  }
}

// ------------------------------------------------- fallback: round-1 fused
__global__ __launch_bounds__(kTHREADS, 2) void fused_conv_fc_kernel(
    const float* __restrict__ data, const float* __restrict__ w1,
    const float* __restrict__ b1, const float* __restrict__ w2,
    const float* __restrict__ b2, const float* __restrict__ wfc,
    const float* __restrict__ bfc, float* __restrict__ out) {
  __shared__ unsigned short Ab[kB * kLDK];
  __shared__ unsigned short Bb[48 * kLDK];
  const int tid = threadIdx.x;
  const int i = blockIdx.x >> 1;
  const int nh = blockIdx.x & 1;
  const int nbase = nh * kNH;
  for (int z = tid; z < 4 * kLDK; z += kTHREADS) Bb[kNH * kLDK + z] = 0;
  float w1r[9], w2r[9];
#pragma unroll
  for (int jj = 0; jj < 9; ++jj) { w1r[jj] = w1[i * 9 + jj]; w2r[jj] = w2[i * 9 + jj]; }
  const float b1r = b1[i], b2r = b2[i];
  const int bb = tid / 6;
  const int oc = tid - bb * 6;
  const int fr0 = oc * 8;
  const float* dbase = data + bb * (kT * kF) + fr0;
  float c1[6][10];
  float dA[12], dB[12], dC[12], dD[12];
  float4 W[6];
  loadrow(dC, dbase + 0 * kF);
  loadrow(dD, dbase + 1 * kF);
  loadrow(dA, dbase + 2 * kF);
  loadrow(dB, dbase + 3 * kF);
  c1row(c1[0], dC, dD, dA, w1r, b1r);
  c1row(c1[1], dD, dA, dB, w1r, b1r);
#pragma unroll
  for (int jj = 0; jj < 6; ++jj) {
    int q = tid + kTHREADS * jj;
    if (q < kNH * 48) {
      int n = q / 48, k4 = q - n * 48;
      W[jj] = *(const float4*)(wfc + (size_t)(i * kN + nbase + n) * kFTOT + k4 * 4);
    } else {
      W[jj] = make_float4(0.f, 0.f, 0.f, 0.f);
    }
  }
  const int wv = tid >> 6, ln = tid & 63;
  const int nt = wv % 3, mp = wv / 3;
  const int lc = ln & 15, lq = ln >> 4;
  f32x4 acc0 = {0.f, 0.f, 0.f, 0.f};
  f32x4 acc1 = {0.f, 0.f, 0.f, 0.f};
  for (int s = 0; s < kSLABS; ++s) {
    loadrow(dC, dbase + (4 * s + 4) * kF);
    c1row(c1[2], dA, dB, dC, w1r, b1r);
    if (s < kSLABS - 1) {
      loadrow(dD, dbase + (4 * s + 5) * kF);
      c1row(c1[3], dB, dC, dD, w1r, b1r);
      loadrow(dA, dbase + (4 * s + 6) * kF);
      c1row(c1[4], dC, dD, dA, w1r, b1r);
      loadrow(dB, dbase + (4 * s + 7) * kF);
      c1row(c1[5], dD, dA, dB, w1r, b1r);
    }
#pragma unroll
    for (int tl = 0; tl < 4; ++tl) {
      if (tl == 0 || s < kSLABS - 1) {
        u16x8 o8;
#pragma unroll
        for (int c = 0; c < 8; ++c) {
          float v = b2r;
#pragma unroll
          for (int r = 0; r < 3; ++r) {
            v += c1[tl + r][c] * w2r[3 * r];
            v += c1[tl + r][c + 1] * w2r[3 * r + 1];
            v += c1[tl + r][c + 2] * w2r[3 * r + 2];
          }
          o8[c] = bf16_rne(fmaxf(v, 0.0f));
        }
        *(u16x8*)&Ab[bb * kLDK + tl * 48 + fr0] = o8;
      }
    }
#pragma unroll
    for (int jj = 0; jj < 6; ++jj) {
      int q = tid + kTHREADS * jj;
      if (q < kNH * 48) {
        int n = q / 48, k4 = q - n * 48;
        u16x4 o;
        o[0] = bf16_rne(W[jj].x); o[1] = bf16_rne(W[jj].y);
        o[2] = bf16_rne(W[jj].z); o[3] = bf16_rne(W[jj].w);
        *(u16x4*)&Bb[n * kLDK + k4 * 4] = o;
      }
    }
    if (s + 1 < kSLABS) {
      const int real4 = (s + 1 == kSLABS - 1) ? 12 : 48;
#pragma unroll
      for (int jj = 0; jj < 6; ++jj) {
        int q = tid + kTHREADS * jj;
        int n = q / 48, k4 = q - n * 48;
        if (q < kNH * 48 && k4 < real4) {
          W[jj] = *(const float4*)(wfc + (size_t)(i * kN + nbase + n) * kFTOT +
                                  (size_t)(s + 1) * 192 + k4 * 4);
        } else {
          W[jj] = make_float4(0.f, 0.f, 0.f, 0.f);
        }
      }
    }
    __syncthreads();
    {
      const unsigned short* Ar0 = &Ab[(mp * 32 + lc) * kLDK];
      const unsigned short* Ar1 = Ar0 + 16 * kLDK;
      const unsigned short* Br = &Bb[(nt * 16 + lc) * kLDK];
      const int kqo = lq * 8;
      const int kmax = (s != kSLABS - 1) ? 6 : 2;
      for (int ks = 0; ks < kmax; ++ks) {
        int ko = ks * 32 + kqo;
        bf16x8 a0 = *(const bf16x8*)(Ar0 + ko);
        bf16x8 a1 = *(const bf16x8*)(Ar1 + ko);
        bf16x8 bfr = *(const bf16x8*)(Br + ko);
        acc0 = __builtin_amdgcn_mfma_f32_16x16x32_bf16(a0, bfr, acc0, 0, 0, 0);
        acc1 = __builtin_amdgcn_mfma_f32_16x16x32_bf16(a1, bfr, acc1, 0, 0, 0);
      }
    }
    __syncthreads();
    if (s < kSLABS - 1) {
#pragma unroll
      for (int c = 0; c < 10; ++c) { c1[0][c] = c1[4][c]; c1[1][c] = c1[5][c]; }
    }
  }
  const int nl = nt * 16 + lc;
  if (nl < kNH) {
    const int ng = nbase + nl;
    const float bias = bfc[i * kN + ng];
#pragma unroll
    for (int r = 0; r < 4; ++r) {
      int b0 = mp * 32 + lq * 4 + r;
      float v0 = acc0[r] + bias;
      out[(size_t)(b0 * kI + i) * kN + ng] = 1.0f / (1.0f + __expf(-v0));
      float v1 = acc1[r] + bias;
      out[(size_t)((b0 + 16) * kI + i) * kN + ng] = 1.0f / (1.0f + __expf(-v1));
    }
  }
}

extern "C" void kernel_launch(void* const* d_in, const int* in_sizes, int n_in,
                              void* d_out, int out_size, void* d_ws, size_t ws_size,
                              hipStream_t stream) {
  const float* data = (const float*)d_in[0];
  const float* w1 = (const float*)d_in[1];
  const float* b1 = (const float*)d_in[2];
  const float* w2 = (const float*)d_in[3];
  const float* b2 = (const float*)d_in[4];
  const float* wfc = (const float*)d_in[5];
  const float* bfc = (const float*)d_in[6];
  float* out = (float*)d_out;
  const size_t need = (size_t)kB * kI * kFTOT * 2 + 64;  // x bf16 (+OOB slack)
  if (ws_size >= need) {
    unsigned short* x = (unsigned short*)d_ws;
    conv_kernel<<<dim3(kI * 4), dim3(kTHREADS), 0, stream>>>(data, w1, b1, w2, b2, x);
    gemm_kernel<<<dim3(kI * 2), dim3(kGTHREADS), 0, stream>>>(x, wfc, bfc, out);
  } else {
    fused_conv_fc_kernel<<<dim3(kI * 2), dim3(kTHREADS), 0, stream>>>(
        data, w1, b1, w2, b2, wfc, bfc, out);
  }
}